// Round 20
// baseline (133.362 us; speedup 1.0000x reference)
//
#include <hip/hip_runtime.h>

#define RES 256
#define THRESH 0.01f
#define GRID_VOX (RES * RES * RES)   // 16,777,216
#define NB 256                       // buckets = ix value
#define CHUNK_REC 8192               // max records per chunk (256 thr * 32)
#define K1_BLOCKS 2048
#define QPT 8                        // quads per thread (32 records)

typedef float vf4 __attribute__((ext_vector_type(4)));
typedef unsigned int u32;
typedef unsigned short u16;
typedef u32 vu4 __attribute__((ext_vector_type(4)));

__device__ __forceinline__ int voxel_coord(float p) {
    // Replicate reference rounding exactly:
    // pts = -1 + p*2 ; coord = ((pts+1)/2)*256 ; trunc ; clamp
    float a = -1.0f + p * 2.0f;              // mul by 2 exact; one rounding
    float c = ((a + 1.0f) * 0.5f) * 256.0f;  // one rounding at (a+1); scalings exact
    int v = (int)c;
    v = v < 0 ? 0 : v;
    v = v > (RES - 1) ? (RES - 1) : v;
    return v;
}

// K1: r19 chassis minus the LDS staging round-trip. Bucket-sorted records go
// DIRECTLY to global as scattered u16 stores: each chunk's 16 KB region is
// L2-resident while hot (8 blocks/CU x 16 KB), so HBM only sees the 16 MB
// writeback; L2 (34.5 TB/s) absorbs the sector traffic. Deletes s_buf
// (LDS 18.4 -> ~2 KB), one barrier, and the copy-out loop. Rank packed in
// rec top byte; 1-quad load batches keep VGPR <= 64 for 8 waves/SIMD.
__global__ __launch_bounds__(256, 8) void k1_bin256(const vf4* __restrict__ pts4,
                                                    const vf4* __restrict__ dens4,
                                                    u16* __restrict__ regions16,
                                                    u32* __restrict__ meta,
                                                    int n4) {
    __shared__ u32 s_cnt[NB];
    __shared__ u32 s_off[NB];

    const int tid  = threadIdx.x;
    const int lane = tid & 63;
    const int wid  = tid >> 6;
    const int T    = gridDim.x * blockDim.x;
    const int t0   = blockIdx.x * blockDim.x + tid;

    s_cnt[tid] = 0;
    __syncthreads();                             // barrier 1

    u32 rec[QPT * 4], vbits = 0;                 // rank in bits 24-31

    #pragma unroll
    for (int s2 = 0; s2 < QPT; ++s2) {           // 8 batches of 1 quad
        int q = t0 + s2 * T;
        if (q < n4) {
            vf4 p0 = pts4[3 * q + 0];
            vf4 p1 = pts4[3 * q + 1];
            vf4 p2 = pts4[3 * q + 2];
            vf4 d  = dens4[q];
            float px[4] = {p0.x, p0.w, p1.z, p2.y};
            float py[4] = {p0.y, p1.x, p1.w, p2.z};
            float pz[4] = {p0.z, p1.y, p2.x, p2.w};
            float dd[4] = {d.x, d.y, d.z, d.w};
            #pragma unroll
            for (int k = 0; k < 4; ++k) {
                int kk = s2 * 4 + k;
                u32 vox = ((u32)voxel_coord(px[k]) << 16) |
                          ((u32)voxel_coord(py[k]) << 8)  |
                           (u32)voxel_coord(pz[k]);
                rec[kk] = vox;
                if (dd[k] > THRESH) {
                    vbits |= 1u << kk;
                    u32 rk = atomicAdd(&s_cnt[vox >> 16], 1u);
                    rec[kk] = vox | (rk << 24);
                }
            }
        } else {
            #pragma unroll
            for (int k = 0; k < 4; ++k) rec[s2 * 4 + k] = 0;
        }
    }
    __syncthreads();                             // barrier 2

    if (wid == 0) {                              // exclusive scan of 256 counts
        u32 c0 = s_cnt[4 * lane + 0], c1 = s_cnt[4 * lane + 1];
        u32 c2 = s_cnt[4 * lane + 2], c3 = s_cnt[4 * lane + 3];
        u32 w = c0 + c1 + c2 + c3;
        u32 x = w;
        #pragma unroll
        for (int dlt = 1; dlt < 64; dlt <<= 1) {
            u32 v = __shfl_up(x, dlt, 64);
            if (lane >= dlt) x += v;
        }
        u32 base = x - w;
        s_off[4 * lane + 0] = base;
        s_off[4 * lane + 1] = base + c0;
        s_off[4 * lane + 2] = base + c0 + c1;
        s_off[4 * lane + 3] = base + c0 + c1 + c2;
    }
    __syncthreads();                             // barrier 3 (last)

    const u32 c = blockIdx.x;                    // chunk id == block

    // meta row: coalesced 1 KB store per chunk
    meta[(size_t)c * NB + tid] = s_off[tid] | (s_cnt[tid] << 16);

    // bucket-sorted records straight to global (u16 scatter into the chunk's
    // 16 KB L2-hot region; distinct addresses -> byte-enable safe)
    u16* reg = regions16 + (size_t)c * CHUNK_REC;
    #pragma unroll
    for (int kk = 0; kk < QPT * 4; ++kk)
        if ((vbits >> kk) & 1u) {
            u32 r = rec[kk];
            reg[s_off[(r >> 16) & 0xFFu] + (r >> 24)] = (u16)r;
        }
}

// K2: r16-exact. One block per ix plane, per-thread chunk gather (2 chunks
// per thread -> short chains, max TLP). Zero 64 KB LDS plane, scatter runs,
// write plane as floats (fused zero-init + expand).
__global__ __launch_bounds__(1024) void k2_plane(const u16* __restrict__ regions16,
                                                 const u32* __restrict__ meta,
                                                 vf4* __restrict__ out4,
                                                 int nchunk) {
    extern __shared__ unsigned char plane[];        // 65536 bytes
    const int ix  = blockIdx.x;
    const int tid = threadIdx.x;

    uint4* p16 = (uint4*)plane;
    #pragma unroll
    for (int j = 0; j < 4; ++j)                     // 4096 uint4 / 1024 thr
        p16[tid + j * 1024] = make_uint4(0u, 0u, 0u, 0u);
    __syncthreads();

    for (int c = tid; c < nchunk; c += 1024) {
        u32 m = meta[(size_t)c * NB + ix];
        u32 off = m & 0xFFFFu;
        u32 cnt = m >> 16;
        const u16* run = regions16 + (size_t)c * CHUNK_REC + off;
        for (u32 j = 0; j < cnt; ++j)
            plane[run[j]] = (unsigned char)1;       // same-value races safe
    }
    __syncthreads();

    const u32* pw = (const u32*)plane;
    vf4* dst = out4 + ((size_t)ix << 14);           // 16384 float4 per plane
    #pragma unroll
    for (int j = 0; j < 16; ++j) {
        int i = tid + j * 1024;
        u32 w = pw[i];
        vf4 f;
        f.x = (w & 0x000000FFu) ? 1.0f : 0.0f;
        f.y = (w & 0x0000FF00u) ? 1.0f : 0.0f;
        f.z = (w & 0x00FF0000u) ? 1.0f : 0.0f;
        f.w = (w & 0xFF000000u) ? 1.0f : 0.0f;
        __builtin_nontemporal_store(f, &dst[i]);
    }
}

// Fallback 1 (ws >= 16 MB): byte-grid scatter + expand (round 3).
__global__ void occ_scatter_bytes(const vf4* __restrict__ pts4,
                                  const vf4* __restrict__ dens4,
                                  unsigned char* __restrict__ bgrid, int n4) {
    int t = blockIdx.x * blockDim.x + threadIdx.x;
    int stride = gridDim.x * blockDim.x;
    for (int i = t; i < n4; i += stride) {
        vf4 p0 = pts4[3 * i + 0];
        vf4 p1 = pts4[3 * i + 1];
        vf4 p2 = pts4[3 * i + 2];
        vf4 d  = dens4[i];
        float px[4] = {p0.x, p0.w, p1.z, p2.y};
        float py[4] = {p0.y, p1.x, p1.w, p2.z};
        float pz[4] = {p0.z, p1.y, p2.x, p2.w};
        float dd[4] = {d.x, d.y, d.z, d.w};
        #pragma unroll
        for (int k = 0; k < 4; ++k) {
            if (dd[k] > THRESH) {
                int ix = voxel_coord(px[k]);
                int iy = voxel_coord(py[k]);
                int iz = voxel_coord(pz[k]);
                bgrid[((ix << 8) | iy) * RES + iz] = (unsigned char)1;
            }
        }
    }
}

__global__ void occ_expand(const uint4* __restrict__ bgrid16,
                           float4* __restrict__ grid4) {
    int i = blockIdx.x * blockDim.x + threadIdx.x;
    uint4 w = bgrid16[i];
    unsigned int ws[4] = {w.x, w.y, w.z, w.w};
    #pragma unroll
    for (int q = 0; q < 4; ++q) {
        unsigned int v = ws[q];
        float4 f;
        f.x = (v & 0x000000FFu) ? 1.0f : 0.0f;
        f.y = (v & 0x0000FF00u) ? 1.0f : 0.0f;
        f.z = (v & 0x00FF0000u) ? 1.0f : 0.0f;
        f.w = (v & 0xFF000000u) ? 1.0f : 0.0f;
        grid4[i * 4 + q] = f;
    }
}

// Fallback 2 (tiny ws): direct float scatter (round 1).
__global__ void occ_scatter_float(const float4* __restrict__ pts4,
                                  const float4* __restrict__ dens4,
                                  float* __restrict__ grid, int n4) {
    int t = blockIdx.x * blockDim.x + threadIdx.x;
    int stride = gridDim.x * blockDim.x;
    for (int i = t; i < n4; i += stride) {
        float4 p0 = pts4[3 * i + 0];
        float4 p1 = pts4[3 * i + 1];
        float4 p2 = pts4[3 * i + 2];
        float4 d  = dens4[i];
        float px[4] = {p0.x, p0.w, p1.z, p2.y};
        float py[4] = {p0.y, p1.x, p1.w, p2.z};
        float pz[4] = {p0.z, p1.y, p2.x, p2.w};
        float dd[4] = {d.x, d.y, d.z, d.w};
        #pragma unroll
        for (int k = 0; k < 4; ++k) {
            if (dd[k] > THRESH) {
                int ix = voxel_coord(px[k]);
                int iy = voxel_coord(py[k]);
                int iz = voxel_coord(pz[k]);
                grid[((ix * RES) + iy) * RES + iz] = 1.0f;
            }
        }
    }
}

extern "C" void kernel_launch(void* const* d_in, const int* in_sizes, int n_in,
                              void* d_out, int out_size, void* d_ws, size_t ws_size,
                              hipStream_t stream) {
    const float* points    = (const float*)d_in[0];   // [N,3]
    const float* densities = (const float*)d_in[1];   // [N]
    float* grid = (float*)d_out;                      // 256^3 floats

    int n  = in_sizes[1];     // 16,000,000
    int n4 = n / 4;

    const int nchunk = K1_BLOCKS;                     // 2048 (one chunk per block)

    // ws layout: [0, metaSize) meta u32[nchunk*256] | regions u16[nchunk*8192]
    size_t metaSize = (size_t)nchunk * NB * sizeof(u32);                // 2 MB
    size_t need = metaSize + (size_t)nchunk * CHUNK_REC * sizeof(u16);  // 34 MB

    // capacity check: K1 grid must cover all quads in one pass
    bool covered = (size_t)K1_BLOCKS * 256 * QPT >= (size_t)n4;

    if (ws_size >= need && covered) {
        u32* meta      = (u32*)d_ws;
        u16* regions16 = (u16*)((char*)d_ws + metaSize);

        // no memset needed: meta fully written by K1, regions bounded by meta
        k1_bin256<<<K1_BLOCKS, 256, 0, stream>>>(
            (const vf4*)points, (const vf4*)densities, regions16, meta, n4);

        k2_plane<<<NB, 1024, 65536, stream>>>(regions16, meta, (vf4*)grid, nchunk);
    } else if (ws_size >= (size_t)GRID_VOX) {
        unsigned char* bgrid = (unsigned char*)d_ws;
        (void)hipMemsetAsync(d_ws, 0, (size_t)GRID_VOX, stream);
        occ_scatter_bytes<<<2048, 256, 0, stream>>>(
            (const vf4*)points, (const vf4*)densities, bgrid, n4);
        occ_expand<<<GRID_VOX / (16 * 256), 256, 0, stream>>>(
            (const uint4*)bgrid, (float4*)grid);
    } else {
        (void)hipMemsetAsync(d_out, 0, (size_t)out_size * sizeof(float), stream);
        occ_scatter_float<<<2048, 256, 0, stream>>>(
            (const float4*)points, (const float4*)densities, grid, n4);
    }
}

// Round 21
// 87.095 us; speedup vs baseline: 1.5312x; 1.5312x over previous
//
#include <hip/hip_runtime.h>

#define RES 256
#define THRESH 0.01f
#define GRID_VOX (RES * RES * RES)   // 16,777,216
#define NB 256                       // buckets = ix value
#define CHUNK_REC 8192               // max records per chunk (256 thr * 32)
#define K1_BLOCKS 2048
#define QPT 8                        // quads per thread (32 records)

typedef float vf4 __attribute__((ext_vector_type(4)));
typedef unsigned int u32;
typedef unsigned short u16;
typedef u32 vu4 __attribute__((ext_vector_type(4)));

__device__ __forceinline__ int voxel_coord(float p) {
    // Replicate reference rounding exactly:
    // pts = -1 + p*2 ; coord = ((pts+1)/2)*256 ; trunc ; clamp
    float a = -1.0f + p * 2.0f;              // mul by 2 exact; one rounding
    float c = ((a + 1.0f) * 0.5f) * 256.0f;  // one rounding at (a+1); scalings exact
    int v = (int)c;
    v = v < 0 ? 0 : v;
    v = v > (RES - 1) ? (RES - 1) : v;
    return v;
}

// K1 (r19, proven 87.3 us total): rank packed into rec top byte
// (rec = vox | rnk<<24, no rnk[] array), 1-quad load batches, u16 LDS
// staging + vu4 copy-out. VGPR <= 64 clean (no spill) -> 8 waves/SIMD.
// Chunk-private regions, no global atomics, no memset.
__global__ __launch_bounds__(256, 8) void k1_bin256(const vf4* __restrict__ pts4,
                                                    const vf4* __restrict__ dens4,
                                                    vu4* __restrict__ regions4,
                                                    u32* __restrict__ meta,
                                                    int n4) {
    __shared__ u32 s_cnt[NB];
    __shared__ u32 s_off[NB];
    __shared__ u32 s_buf32[CHUNK_REC / 2];   // 8192 u16 records = 16 KB
    u16* s_buf16 = (u16*)s_buf32;

    const int tid  = threadIdx.x;
    const int lane = tid & 63;
    const int wid  = tid >> 6;
    const int T    = gridDim.x * blockDim.x;
    const int t0   = blockIdx.x * blockDim.x + tid;

    s_cnt[tid] = 0;
    __syncthreads();

    u32 rec[QPT * 4], vbits = 0;             // rank lives in bits 24-31 of rec

    #pragma unroll
    for (int s2 = 0; s2 < QPT; ++s2) {       // 8 batches of 1 quad
        int q = t0 + s2 * T;
        if (q < n4) {
            vf4 p0 = pts4[3 * q + 0];
            vf4 p1 = pts4[3 * q + 1];
            vf4 p2 = pts4[3 * q + 2];
            vf4 d  = dens4[q];
            float px[4] = {p0.x, p0.w, p1.z, p2.y};
            float py[4] = {p0.y, p1.x, p1.w, p2.z};
            float pz[4] = {p0.z, p1.y, p2.x, p2.w};
            float dd[4] = {d.x, d.y, d.z, d.w};
            #pragma unroll
            for (int k = 0; k < 4; ++k) {
                int kk = s2 * 4 + k;
                u32 vox = ((u32)voxel_coord(px[k]) << 16) |
                          ((u32)voxel_coord(py[k]) << 8)  |
                           (u32)voxel_coord(pz[k]);
                rec[kk] = vox;
                if (dd[k] > THRESH) {
                    vbits |= 1u << kk;
                    u32 rk = atomicAdd(&s_cnt[vox >> 16], 1u);
                    rec[kk] = vox | (rk << 24);
                }
            }
        } else {
            #pragma unroll
            for (int k = 0; k < 4; ++k) rec[s2 * 4 + k] = 0;
        }
    }
    __syncthreads();

    if (wid == 0) {                              // exclusive scan of 256 counts
        u32 c0 = s_cnt[4 * lane + 0], c1 = s_cnt[4 * lane + 1];
        u32 c2 = s_cnt[4 * lane + 2], c3 = s_cnt[4 * lane + 3];
        u32 w = c0 + c1 + c2 + c3;
        u32 x = w;
        #pragma unroll
        for (int dlt = 1; dlt < 64; dlt <<= 1) {
            u32 v = __shfl_up(x, dlt, 64);
            if (lane >= dlt) x += v;
        }
        u32 base = x - w;
        s_off[4 * lane + 0] = base;
        s_off[4 * lane + 1] = base + c0;
        s_off[4 * lane + 2] = base + c0 + c1;
        s_off[4 * lane + 3] = base + c0 + c1 + c2;
    }
    __syncthreads();

    const u32 c = blockIdx.x;                    // chunk id == block

    // meta row: coalesced 1 KB store per chunk
    meta[(size_t)c * NB + tid] = s_off[tid] | (s_cnt[tid] << 16);

    // stage bucket-sorted u16 records (unpack bucket+rank from rec)
    #pragma unroll
    for (int kk = 0; kk < QPT * 4; ++kk)
        if ((vbits >> kk) & 1u) {
            u32 r = rec[kk];
            u32 addr = s_off[(r >> 16) & 0xFFu] + (r >> 24);
            s_buf16[addr] = (u16)r;
        }
    __syncthreads();

    // copy-out: contiguous coalesced vu4 bursts straight from the u16 buffer
    u32 total = s_off[NB - 1] + s_cnt[NB - 1];
    u32 n16 = (total + 7) >> 3;                  // # of vu4 stores (8 recs each)
    vu4* reg = regions4 + (size_t)c * (CHUNK_REC / 8);
    const vu4* sb4 = (const vu4*)s_buf32;
    for (u32 idx = tid; idx < n16; idx += 256u)
        reg[idx] = sb4[idx];                     // trailing garbage never read
}

// K2: one block per ix plane, per-thread chunk gather (2 chunks per thread
// -> short chains, max TLP). Zero 64 KB LDS plane, scatter runs, write plane
// as floats (fused zero-init + expand).
__global__ __launch_bounds__(1024) void k2_plane(const u16* __restrict__ regions16,
                                                 const u32* __restrict__ meta,
                                                 vf4* __restrict__ out4,
                                                 int nchunk) {
    extern __shared__ unsigned char plane[];        // 65536 bytes
    const int ix  = blockIdx.x;
    const int tid = threadIdx.x;

    uint4* p16 = (uint4*)plane;
    #pragma unroll
    for (int j = 0; j < 4; ++j)                     // 4096 uint4 / 1024 thr
        p16[tid + j * 1024] = make_uint4(0u, 0u, 0u, 0u);
    __syncthreads();

    for (int c = tid; c < nchunk; c += 1024) {
        u32 m = meta[(size_t)c * NB + ix];
        u32 off = m & 0xFFFFu;
        u32 cnt = m >> 16;
        const u16* run = regions16 + (size_t)c * CHUNK_REC + off;
        for (u32 j = 0; j < cnt; ++j)
            plane[run[j]] = (unsigned char)1;       // same-value races safe
    }
    __syncthreads();

    const u32* pw = (const u32*)plane;
    vf4* dst = out4 + ((size_t)ix << 14);           // 16384 float4 per plane
    #pragma unroll
    for (int j = 0; j < 16; ++j) {
        int i = tid + j * 1024;
        u32 w = pw[i];
        vf4 f;
        f.x = (w & 0x000000FFu) ? 1.0f : 0.0f;
        f.y = (w & 0x0000FF00u) ? 1.0f : 0.0f;
        f.z = (w & 0x00FF0000u) ? 1.0f : 0.0f;
        f.w = (w & 0xFF000000u) ? 1.0f : 0.0f;
        __builtin_nontemporal_store(f, &dst[i]);
    }
}

// Fallback 1 (ws >= 16 MB): byte-grid scatter + expand (round 3).
__global__ void occ_scatter_bytes(const vf4* __restrict__ pts4,
                                  const vf4* __restrict__ dens4,
                                  unsigned char* __restrict__ bgrid, int n4) {
    int t = blockIdx.x * blockDim.x + threadIdx.x;
    int stride = gridDim.x * blockDim.x;
    for (int i = t; i < n4; i += stride) {
        vf4 p0 = pts4[3 * i + 0];
        vf4 p1 = pts4[3 * i + 1];
        vf4 p2 = pts4[3 * i + 2];
        vf4 d  = dens4[i];
        float px[4] = {p0.x, p0.w, p1.z, p2.y};
        float py[4] = {p0.y, p1.x, p1.w, p2.z};
        float pz[4] = {p0.z, p1.y, p2.x, p2.w};
        float dd[4] = {d.x, d.y, d.z, d.w};
        #pragma unroll
        for (int k = 0; k < 4; ++k) {
            if (dd[k] > THRESH) {
                int ix = voxel_coord(px[k]);
                int iy = voxel_coord(py[k]);
                int iz = voxel_coord(pz[k]);
                bgrid[((ix << 8) | iy) * RES + iz] = (unsigned char)1;
            }
        }
    }
}

__global__ void occ_expand(const uint4* __restrict__ bgrid16,
                           float4* __restrict__ grid4) {
    int i = blockIdx.x * blockDim.x + threadIdx.x;
    uint4 w = bgrid16[i];
    unsigned int ws[4] = {w.x, w.y, w.z, w.w};
    #pragma unroll
    for (int q = 0; q < 4; ++q) {
        unsigned int v = ws[q];
        float4 f;
        f.x = (v & 0x000000FFu) ? 1.0f : 0.0f;
        f.y = (v & 0x0000FF00u) ? 1.0f : 0.0f;
        f.z = (v & 0x00FF0000u) ? 1.0f : 0.0f;
        f.w = (v & 0xFF000000u) ? 1.0f : 0.0f;
        grid4[i * 4 + q] = f;
    }
}

// Fallback 2 (tiny ws): direct float scatter (round 1).
__global__ void occ_scatter_float(const float4* __restrict__ pts4,
                                  const float4* __restrict__ dens4,
                                  float* __restrict__ grid, int n4) {
    int t = blockIdx.x * blockDim.x + threadIdx.x;
    int stride = gridDim.x * blockDim.x;
    for (int i = t; i < n4; i += stride) {
        float4 p0 = pts4[3 * i + 0];
        float4 p1 = pts4[3 * i + 1];
        float4 p2 = pts4[3 * i + 2];
        float4 d  = dens4[i];
        float px[4] = {p0.x, p0.w, p1.z, p2.y};
        float py[4] = {p0.y, p1.x, p1.w, p2.z};
        float pz[4] = {p0.z, p1.y, p2.x, p2.w};
        float dd[4] = {d.x, d.y, d.z, d.w};
        #pragma unroll
        for (int k = 0; k < 4; ++k) {
            if (dd[k] > THRESH) {
                int ix = voxel_coord(px[k]);
                int iy = voxel_coord(py[k]);
                int iz = voxel_coord(pz[k]);
                grid[((ix * RES) + iy) * RES + iz] = 1.0f;
            }
        }
    }
}

extern "C" void kernel_launch(void* const* d_in, const int* in_sizes, int n_in,
                              void* d_out, int out_size, void* d_ws, size_t ws_size,
                              hipStream_t stream) {
    const float* points    = (const float*)d_in[0];   // [N,3]
    const float* densities = (const float*)d_in[1];   // [N]
    float* grid = (float*)d_out;                      // 256^3 floats

    int n  = in_sizes[1];     // 16,000,000
    int n4 = n / 4;

    const int nchunk = K1_BLOCKS;                     // 2048 (one chunk per block)

    // ws layout: [0, metaSize) meta u32[nchunk*256] | regions u16[nchunk*8192]
    size_t metaSize = (size_t)nchunk * NB * sizeof(u32);                // 2 MB
    size_t need = metaSize + (size_t)nchunk * CHUNK_REC * sizeof(u16);  // 34 MB

    // capacity check: K1 grid must cover all quads in one pass
    bool covered = (size_t)K1_BLOCKS * 256 * QPT >= (size_t)n4;

    if (ws_size >= need && covered) {
        u32* meta     = (u32*)d_ws;
        vu4* regions4 = (vu4*)((char*)d_ws + metaSize);
        const u16* regions16 = (const u16*)regions4;

        // no memset needed: meta fully written by K1, regions bounded by meta
        k1_bin256<<<K1_BLOCKS, 256, 0, stream>>>(
            (const vf4*)points, (const vf4*)densities, regions4, meta, n4);

        k2_plane<<<NB, 1024, 65536, stream>>>(regions16, meta, (vf4*)grid, nchunk);
    } else if (ws_size >= (size_t)GRID_VOX) {
        unsigned char* bgrid = (unsigned char*)d_ws;
        (void)hipMemsetAsync(d_ws, 0, (size_t)GRID_VOX, stream);
        occ_scatter_bytes<<<2048, 256, 0, stream>>>(
            (const vf4*)points, (const vf4*)densities, bgrid, n4);
        occ_expand<<<GRID_VOX / (16 * 256), 256, 0, stream>>>(
            (const uint4*)bgrid, (float4*)grid);
    } else {
        (void)hipMemsetAsync(d_out, 0, (size_t)out_size * sizeof(float), stream);
        occ_scatter_float<<<2048, 256, 0, stream>>>(
            (const float4*)points, (const float4*)densities, grid, n4);
    }
}